// Round 11
// baseline (120.667 us; speedup 1.0000x reference)
//
#include <hip/hip_runtime.h>
#include <math.h>

typedef float f32x4 __attribute__((ext_vector_type(4)));
typedef __bf16 bf16x8 __attribute__((ext_vector_type(8)));
typedef unsigned short u16x8 __attribute__((ext_vector_type(8)));
typedef unsigned short u16x4 __attribute__((ext_vector_type(4)));
typedef unsigned int u32x4 __attribute__((ext_vector_type(4)));

#define MFMA(a, b, c) __builtin_amdgcn_mfma_f32_16x16x32_bf16((a), (b), (c), 0, 0, 0)

static __device__ __forceinline__ unsigned short f2bf(float f) {
  unsigned u = __float_as_uint(f);
  u += 0x7FFFu + ((u >> 16) & 1u);  // RNE
  return (unsigned short)(u >> 16);
}
static __device__ __forceinline__ float bf2f(unsigned short s) {
  return __uint_as_float(((unsigned)s) << 16);
}
static __device__ __forceinline__ unsigned cvt_pk(float lo, float hi) {  // RNE, 1 instr
  unsigned r;
  asm("v_cvt_pk_bf16_f32 %0, %1, %2" : "=v"(r) : "v"(lo), "v"(hi));
  return r;
}

// Bijective XOR swizzles (byte addresses); all in-loop patterns <=2-way (free).
static __device__ __forceinline__ int swz512(int row, int col) {  // rowbytes 512
  return row * 512 + (col ^ ((((row & 7) ^ (col >> 6)) & 7) << 4));
}
static __device__ __forceinline__ int swzV(int d, int col) {      // rowbytes 64
  return d * 64 + (col ^ (((d >> 1) & 3) << 4));
}
static __device__ __forceinline__ int swzO(int d, int col) {      // rowbytes 256
  return d * 256 + (col ^ ((((d & 7) ^ (col >> 7)) & 7) << 4));
}

// ---------- kernel 0 (setup): weight repack (K-chunked) + LN scalars + task sort ----------
// wPk layout: [kk(8)][d(256)][e'(32)]  where element (d,e) -> chunk e>>5, minor e&31.
__global__ __launch_bounds__(256) void setup(
    const float* __restrict__ w0m, const float* __restrict__ w1m, const float* __restrict__ w2m,
    unsigned short* __restrict__ t0m, unsigned short* __restrict__ t1m, unsigned short* __restrict__ t2m,
    const float* __restrict__ w_mlp, const float* __restrict__ b_mlp, float* __restrict__ lnsc,
    const int* __restrict__ vlen, int* __restrict__ tasktab) {
  int bid = blockIdx.x;
  int t = threadIdx.x;
  if (bid == 48) {  // 9 LN scalars: sums of {w0,w1,b, w0^2,w1^2,w0w1,w0b,w1b,b^2}
    float w0 = w_mlp[t], w1 = w_mlp[256 + t], bb = b_mlp[t];
    float v[9] = {w0, w1, bb, w0 * w0, w1 * w1, w0 * w1, w0 * bb, w1 * bb, bb * bb};
    __shared__ float red[4][9];
#pragma unroll
    for (int j = 0; j < 9; ++j) {
      float s = v[j];
#pragma unroll
      for (int off = 32; off >= 1; off >>= 1) s += __shfl_xor(s, off, 64);
      v[j] = s;
    }
    if ((t & 63) == 0)
      for (int j = 0; j < 9; ++j) red[t >> 6][j] = v[j];
    __syncthreads();
    if (t < 9) lnsc[t] = red[0][t] + red[1][t] + red[2][t] + red[3][t];
    return;
  }
  if (bid == 49) {  // sort batches by vl desc; XCD-stratified task table (256 tasks)
    __shared__ int srank[64];
    if (t < 64) {
      int vb = vlen[t], r = 0;
      for (int j = 0; j < 64; ++j) {
        int vj = vlen[j];
        r += (vj > vb) || (vj == vb && j < t);
      }
      srank[r] = t;
    }
    __syncthreads();
    if (t < 64) {
      int r = t, b = srank[r];
      int xcd = r & 7, a = r >> 3;  // all 4 tiles of batch b on XCD xcd (K/V L2 reuse)
      for (int tt = 0; tt < 4; ++tt)
        tasktab[(a * 4 + tt) * 8 + xcd] = (b << 2) | tt;
    }
    return;
  }
  // transpose + K-chunk pack: element (e,d) of w -> wPk[e>>5][d][e&31]
  int m = bid >> 4, t16 = bid & 15;
  const float* w = (m == 0) ? w0m : (m == 1) ? w1m : w2m;
  unsigned short* o = (m == 0) ? t0m : (m == 1) ? t1m : t2m;
  __shared__ float sm[64][65];
  int bi = t16 >> 2, bj = t16 & 3;
  for (int kb = 0; kb < 16; ++kb) {
    int idx = kb * 256 + t;
    int r = idx >> 6, c = idx & 63;
    sm[r][c] = w[(bi * 64 + r) * 256 + bj * 64 + c];
  }
  __syncthreads();
  for (int kb = 0; kb < 16; ++kb) {
    int idx = kb * 256 + t;
    int r = idx >> 6, c = idx & 63;
    int d = bj * 64 + r, e = bi * 64 + c;
    o[(e >> 5) * 8192 + d * 32 + (e & 31)] = f2bf(sm[c][r]);
  }
}

// ---------- barrier-free GEMM: B fragments stream straight from global (L2-hot) ----------
static __device__ __forceinline__ void gemm_direct(
    const unsigned short* __restrict__ Bpk, const unsigned short* Alds,
    int w, int g, int c15, f32x4 (&acc)[4][4]) {
  const unsigned short* bp = Bpk + (w * 64 + c15) * 32 + 8 * g;
#pragma unroll
  for (int c = 0; c < 8; ++c) {
    bf16x8 bfv[4];
#pragma unroll
    for (int nt = 0; nt < 4; ++nt)
      bfv[nt] = *(const bf16x8*)(bp + c * 8192 + nt * 512);
    bf16x8 af[4];
#pragma unroll
    for (int at = 0; at < 4; ++at)
      af[at] = *(const bf16x8*)((char*)Alds + swz512(at * 16 + c15, c * 64 + 16 * g));
    __builtin_amdgcn_s_setprio(1);
#pragma unroll
    for (int at = 0; at < 4; ++at)
#pragma unroll
      for (int nt = 0; nt < 4; ++nt) acc[at][nt] = MFMA(af[at], bfv[nt], acc[at][nt]);
    __builtin_amdgcn_s_setprio(0);
  }
}

// ---------- kernel 1: fused k+v projections, wave-split (512 blocks x 512 thr) ----------
// Waves 0-3: V GEMM + direct vT stores. Waves 4-7: K GEMM -> Klds transpose buffer.
__global__ __launch_bounds__(512, 4) void gemms(
    const float* __restrict__ h, const int* __restrict__ vlen,
    const unsigned short* __restrict__ wkPk, const float* __restrict__ bk,
    const unsigned short* __restrict__ wvPk, const float* __restrict__ bv,
    unsigned short* __restrict__ kout, unsigned short* __restrict__ vT) {
  __shared__ unsigned short Alds[64 * 256];  // 32KB
  __shared__ unsigned short Klds[64 * 256];  // 32KB
  int tid = threadIdx.x, w = tid >> 6, lane = tid & 63, g = lane >> 4, c15 = lane & 15;
  int tile = blockIdx.x;
  int b = tile >> 3;
  int nbase = (tile & 7) * 64;
  if (nbase >= vlen[b]) return;
  f32x4 acc[4][4];
  {
    const float* hb = h + (size_t)tile * 16384;
    f32x4 ha[4], hc[4];
#pragma unroll
    for (int i = 0; i < 4; ++i) {  // 2KB contiguous per wave-instruction pair
      ha[i] = *(const f32x4*)(hb + i * 4096 + tid * 8);
      hc[i] = *(const f32x4*)(hb + i * 4096 + tid * 8 + 4);
    }
#pragma unroll
    for (int i = 0; i < 4; ++i) {
      u16x8 pk;
#pragma unroll
      for (int j = 0; j < 4; ++j) { pk[j] = f2bf(ha[i][j]); pk[j + 4] = f2bf(hc[i][j]); }
      *(u16x8*)((char*)Alds + swz512(i * 16 + (tid >> 5), (tid & 31) * 16)) = pk;
    }
  }
#pragma unroll
  for (int a = 0; a < 4; ++a)
#pragma unroll
    for (int n = 0; n < 4; ++n) acc[a][n] = (f32x4){0.f, 0.f, 0.f, 0.f};
  __syncthreads();

  int w4 = w & 3;
  if (w < 4) {  // --- V: direct-to-global vT stores ---
    gemm_direct(wvPk, Alds, w4, g, c15, acc);
#pragma unroll
    for (int at = 0; at < 4; ++at)
#pragma unroll
      for (int nt = 0; nt < 4; ++nt) {
        int col = w4 * 64 + nt * 16 + c15;
        float bb = bv[col];
        u16x4 o;
#pragma unroll
        for (int r = 0; r < 4; ++r) o[r] = f2bf(acc[at][nt][r] + bb);
        *(u16x4*)(vT + (size_t)b * 131072 + (size_t)col * 512 + nbase + at * 16 + 4 * g) = o;
      }
  } else {  // --- K: into Klds for transpose ---
    gemm_direct(wkPk, Alds, w4, g, c15, acc);
#pragma unroll
    for (int at = 0; at < 4; ++at)
#pragma unroll
      for (int nt = 0; nt < 4; ++nt) {
        int col = w4 * 64 + nt * 16 + c15;
        float bb = bk[col];
#pragma unroll
        for (int r = 0; r < 4; ++r)
          *(unsigned short*)((char*)Klds + swz512(at * 16 + 4 * g + r, col * 2)) =
              f2bf(acc[at][nt][r] + bb);
      }
  }
  __syncthreads();
  if (tid < 256) {  // coalesced k store (v-waves, now free)
    int row = tid >> 2;
    for (int i = 0; i < 8; ++i) {
      int colb = (tid & 3) * 128 + i * 16;
      u16x8 vv = *(const u16x8*)((char*)Klds + swz512(row, colb));
      *(u16x8*)(kout + (size_t)(tile * 64 + row) * 256 + colb / 2) = vv;
    }
  }
}

// ---------- kernel 2: attention + fused q projection ----------
// 512 threads / 8 waves, ALL consumers. Wave w: query group qg=w&3 (32 queries,
// 2 q-frags share each kf/vf read), phase ph=w>>2 computes chunks 2t+ph.
// Each chunk read by 4 waves (not 8) -> LDS-read traffic halved. 4-slot 128KB
// ring, reg-staging interleaved; one barrier per chunk-pair. f32 LDS combine.
__global__ __launch_bounds__(512, 2) void attn(
    const float* __restrict__ traj, const int* __restrict__ labels,
    const float* __restrict__ emb, const float* __restrict__ w_mlp,
    const float* __restrict__ b_mlp, const float* __restrict__ ln_g,
    const float* __restrict__ ln_b, const float* __restrict__ lnsc,
    const unsigned short* __restrict__ wqPk, const float* __restrict__ bq,
    const unsigned short* __restrict__ k, const unsigned short* __restrict__ vT,
    const int* __restrict__ valid_len, const int* __restrict__ tasktab,
    float* __restrict__ partial) {
  __shared__ unsigned short buf[4][16384];  // 128KB: x/q tile overlay, then 4-slot K|V ring
  __shared__ float rsbuf[2][4][64];         // 2KB rs combine

  int task = tasktab[blockIdx.x];
  int b = task >> 2, tt = task & 3;
  int tid = threadIdx.x, w = tid >> 6, lane = tid & 63, g = lane >> 4, c15 = lane & 15;
  int vl = valid_len[b];
  int nit = (vl + 31) >> 5;
  int qg = w & 3;   // query group (32 queries)
  int ph = w >> 2;  // key phase 0/1

  // ---- stage x tile [128 rows][256] (LN(traj@w_mlp+b)+le) into buf (512 thr) ----
  {
    int rrow = tid >> 5, cb = (tid & 31) * 8;
    int lab = labels[b];
    f32x4 wa0 = *(const f32x4*)(w_mlp + cb), wa1 = *(const f32x4*)(w_mlp + cb + 4);
    f32x4 wb0 = *(const f32x4*)(w_mlp + 256 + cb), wb1 = *(const f32x4*)(w_mlp + 256 + cb + 4);
    f32x4 bm0 = *(const f32x4*)(b_mlp + cb), bm1 = *(const f32x4*)(b_mlp + cb + 4);
    f32x4 g0 = *(const f32x4*)(ln_g + cb), g1 = *(const f32x4*)(ln_g + cb + 4);
    f32x4 lb0 = *(const f32x4*)(ln_b + cb), lb1 = *(const f32x4*)(ln_b + cb + 4);
    f32x4 le0 = *(const f32x4*)(emb + lab * 256 + cb), le1 = *(const f32x4*)(emb + lab * 256 + cb + 4);
    float s0 = lnsc[0], s1 = lnsc[1], s2 = lnsc[2], s3 = lnsc[3], s4_ = lnsc[4],
          s5 = lnsc[5], s6 = lnsc[6], s7 = lnsc[7], s8 = lnsc[8];
#pragma unroll
    for (int i = 0; i < 8; ++i) {
      int row = i * 16 + rrow, grow = b * 512 + tt * 128 + row;
      float t0 = traj[grow * 2], t1 = traj[grow * 2 + 1];
      float mu = (t0 * s0 + t1 * s1 + s2) * (1.f / 256.f);
      float ea2 = (t0 * t0 * s3 + t1 * t1 * s4_ + s8 +
                   2.f * (t0 * t1 * s5 + t0 * s6 + t1 * s7)) * (1.f / 256.f);
      float rstd = rsqrtf(ea2 - mu * mu + 1e-5f);
      u16x8 pk;
#pragma unroll
      for (int j = 0; j < 4; ++j) {
        float a0 = t0 * wa0[j] + t1 * wb0[j] + bm0[j];
        float y0 = (a0 - mu) * rstd * g0[j] + lb0[j];
        pk[j] = f2bf((y0 > 0.f ? y0 : 0.01f * y0) + le0[j]);
        float a1 = t0 * wa1[j] + t1 * wb1[j] + bm1[j];
        float y1 = (a1 - mu) * rstd * g1[j] + lb1[j];
        pk[j + 4] = f2bf((y1 > 0.f ? y1 : 0.01f * y1) + le1[j]);
      }
      *(u16x8*)((char*)buf + swz512(row, cb * 2)) = pk;
    }
  }
  __syncthreads();

  // ---- q GEMM 128x256 over 8 waves: rows ph*64+at*16, cols qg*64+nt*16 ----
  {
    f32x4 qacc[4][4];
#pragma unroll
    for (int a = 0; a < 4; ++a)
#pragma unroll
      for (int n = 0; n < 4; ++n) qacc[a][n] = (f32x4){0.f, 0.f, 0.f, 0.f};
    int rbase = ph * 64;
    const unsigned short* bp = wqPk + (qg * 64 + c15) * 32 + 8 * g;
#pragma unroll
    for (int c = 0; c < 8; ++c) {
      bf16x8 bfv[4];
#pragma unroll
      for (int nt = 0; nt < 4; ++nt)
        bfv[nt] = *(const bf16x8*)(bp + c * 8192 + nt * 512);
      bf16x8 af[4];
#pragma unroll
      for (int at = 0; at < 4; ++at)
        af[at] = *(const bf16x8*)((char*)buf + swz512(rbase + at * 16 + c15, c * 64 + 16 * g));
      __builtin_amdgcn_s_setprio(1);
#pragma unroll
      for (int at = 0; at < 4; ++at)
#pragma unroll
        for (int nt = 0; nt < 4; ++nt) qacc[at][nt] = MFMA(af[at], bfv[nt], qacc[at][nt]);
      __builtin_amdgcn_s_setprio(0);
    }
    __syncthreads();  // done reading x
#pragma unroll
    for (int nt = 0; nt < 4; ++nt) {
      int col = qg * 64 + nt * 16 + c15;
      float bb = bq[col];
#pragma unroll
      for (int at = 0; at < 4; ++at)
#pragma unroll
        for (int r = 0; r < 4; ++r)
          *(unsigned short*)((char*)buf + swz512(rbase + at * 16 + 4 * g + r, col * 2)) =
              f2bf(qacc[at][nt][r] + bb);
    }
  }
  __syncthreads();
  bf16x8 qf[2][8];  // wave's 32 queries: qt*64 + qg*16 + c15
#pragma unroll
  for (int qt = 0; qt < 2; ++qt)
#pragma unroll
    for (int kk = 0; kk < 8; ++kk)
      qf[qt][kk] = *(const bf16x8*)((char*)buf + swz512(qt * 64 + qg * 16 + c15, kk * 64 + 16 * g));
  __syncthreads();  // q-tile consumed; buf free for K/V ring

  f32x4 acco[2][16];
#pragma unroll
  for (int qt = 0; qt < 2; ++qt)
#pragma unroll
    for (int i = 0; i < 16; ++i) acco[qt][i] = (f32x4){0.f, 0.f, 0.f, 0.f};
  float rs[2] = {0.f, 0.f};

  const unsigned short* kbase = k + (size_t)b * 512 * 256;
  const unsigned short* vbase = vT + (size_t)b * 131072;
  u16x8 kpre[2], vpre[2];

  auto STAGE_REGS = [&](int n0) {
#pragma unroll
    for (int i = 0; i < 2; ++i) {
      int idx = tid + 512 * i, key = idx >> 5, s = idx & 31;
      kpre[i] = *(const u16x8*)(kbase + (size_t)(n0 + key) * 256 + s * 8);
    }
#pragma unroll
    for (int i = 0; i < 2; ++i) {
      int idx = tid + 512 * i, d = idx >> 2, s = idx & 3;
      vpre[i] = *(const u16x8*)(vbase + (size_t)d * 512 + n0 + s * 8);
    }
  };
  auto WRITE = [&](int slot) {
    char* base = (char*)buf + slot * 32768;
#pragma unroll
    for (int i = 0; i < 2; ++i) {
      int idx = tid + 512 * i, key = idx >> 5, s = idx & 31;
      *(u16x8*)(base + swz512(key, s * 16)) = kpre[i];
    }
#pragma unroll
    for (int i = 0; i < 2; ++i) {
      int idx = tid + 512 * i, d = idx >> 2, s = idx & 3;
      *(u16x8*)(base + 16384 + swzV(d, s * 16)) = vpre[i];
    }
  };

  // ---- prologue: chunks 0,1 -> slots 0,1; chunk 2 -> regs ----
  STAGE_REGS(0);
  WRITE(0);
  if (nit > 1) { STAGE_REGS(32); WRITE(1); }
  if (nit > 2) STAGE_REGS(64);
  __syncthreads();

  // ---- pair loop: my chunk m = 2*it2+ph; stage chunks 2it2+2 / 2it2+3 around it ----
  int npair = (nit + 1) >> 1;
  for (int it2 = 0; it2 < npair; ++it2) {
    int c2 = 2 * it2 + 2, c3 = 2 * it2 + 3;
    if (c2 < nit) WRITE(c2 & 3);
    if (c3 < nit) STAGE_REGS(c3 * 32);
    int m = 2 * it2 + ph;
    if (m < nit) {
      const char* base = (const char*)buf + (m & 3) * 32768;
      int n0 = m * 32;
      // QK^T swapped: lane holds q=c15 (per qt), keys 4g+r per 16-chunk; kf shared
      f32x4 s4[2][2];
#pragma unroll
      for (int qt = 0; qt < 2; ++qt)
#pragma unroll
        for (int c = 0; c < 2; ++c) s4[qt][c] = (f32x4){0.f, 0.f, 0.f, 0.f};
      __builtin_amdgcn_s_setprio(1);
#pragma unroll
      for (int c = 0; c < 2; ++c)
#pragma unroll
        for (int kk = 0; kk < 8; ++kk) {
          bf16x8 kf = *(const bf16x8*)(base + swz512(c * 16 + c15, kk * 64 + 16 * g));
          s4[0][c] = MFMA(kf, qf[0][kk], s4[0][c]);
          s4[1][c] = MFMA(kf, qf[1][kk], s4[1][c]);
        }
      __builtin_amdgcn_s_setprio(0);
      unsigned u01[2][2], u23[2][2];
#pragma unroll
      for (int qt = 0; qt < 2; ++qt)
#pragma unroll
        for (int c = 0; c < 2; ++c) {
          float p4[4];
#pragma unroll
          for (int r = 0; r < 4; ++r) {
            int key = n0 + c * 16 + 4 * g + r;
            float pv = (key < vl) ? __expf(s4[qt][c][r] * 0.0625f) : 0.f;
            p4[r] = pv;
            rs[qt] += pv;
          }
          u01[qt][c] = cvt_pk(p4[0], p4[1]);
          u23[qt][c] = cvt_pk(p4[2], p4[3]);
        }
      // g-exchange: lane needs P[q=c15][keys 8g..8g+7]
      int srcA = c15 | ((lane & 16) << 1);
      int srcB = srcA + 16;
      bool hi = g >= 2;
      union { u32x4 u; bf16x8 v; } pa[2];
#pragma unroll
      for (int qt = 0; qt < 2; ++qt) {
        unsigned x0a = (unsigned)__shfl((int)u01[qt][0], srcA, 64);
        unsigned x1a = (unsigned)__shfl((int)u01[qt][1], srcA, 64);
        unsigned x0b = (unsigned)__shfl((int)u23[qt][0], srcA, 64);
        unsigned x1b = (unsigned)__shfl((int)u23[qt][1], srcA, 64);
        unsigned x0c = (unsigned)__shfl((int)u01[qt][0], srcB, 64);
        unsigned x1c = (unsigned)__shfl((int)u01[qt][1], srcB, 64);
        unsigned x0d = (unsigned)__shfl((int)u23[qt][0], srcB, 64);
        unsigned x1d = (unsigned)__shfl((int)u23[qt][1], srcB, 64);
        pa[qt].u[0] = hi ? x1a : x0a;
        pa[qt].u[1] = hi ? x1b : x0b;
        pa[qt].u[2] = hi ? x1c : x0c;
        pa[qt].u[3] = hi ? x1d : x0d;
      }
      // PV swapped: O^T[d][q] += V^T * P^T; vf shared by both qt
      __builtin_amdgcn_s_setprio(1);
#pragma unroll
      for (int dt = 0; dt < 16; ++dt) {
        bf16x8 vf = *(const bf16x8*)(base + 16384 + swzV(dt * 16 + c15, 16 * g));
        acco[0][dt] = MFMA(vf, pa[0].v, acco[0][dt]);
        acco[1][dt] = MFMA(vf, pa[1].v, acco[1][dt]);
      }
      __builtin_amdgcn_s_setprio(0);
    }
    if (c3 < nit) WRITE(c3 & 3);
    if (c2 + 2 < nit) STAGE_REGS((c2 + 2) * 32);
    __syncthreads();
  }

  // ---- rs g-reduce, then pair combine: ph1 -> LDS f32, ph0 adds ----
#pragma unroll
  for (int qt = 0; qt < 2; ++qt) {
    rs[qt] += __shfl_xor(rs[qt], 16, 64);
    rs[qt] += __shfl_xor(rs[qt], 32, 64);
  }
  float* cbuf = (float*)buf;  // 32768 f32 (128KB)
  if (ph == 1) {
#pragma unroll
    for (int qt = 0; qt < 2; ++qt)
#pragma unroll
      for (int dt = 0; dt < 16; ++dt)
#pragma unroll
        for (int r = 0; r < 4; ++r)
          cbuf[((qt * 4 + qg) * 64 + dt * 4 + r) * 64 + lane] = acco[qt][dt][r];
    rsbuf[0][qg][lane] = rs[0];
    rsbuf[1][qg][lane] = rs[1];
  }
  __syncthreads();
  float inv[2];
  if (ph == 0) {
#pragma unroll
    for (int qt = 0; qt < 2; ++qt)
#pragma unroll
      for (int dt = 0; dt < 16; ++dt)
#pragma unroll
        for (int r = 0; r < 4; ++r)
          acco[qt][dt][r] += cbuf[((qt * 4 + qg) * 64 + dt * 4 + r) * 64 + lane];
    rs[0] += rsbuf[0][qg][lane];
    rs[1] += rsbuf[1][qg][lane];
    inv[0] = 1.f / rs[0];
    inv[1] = 1.f / rs[1];
  }
  __syncthreads();  // cbuf free; overlay buf as O^T[256d][256B]
  if (ph == 0) {
#pragma unroll
    for (int qt = 0; qt < 2; ++qt) {
      int qcol = qt * 64 + qg * 16 + c15;  // 0..127
#pragma unroll
      for (int dt = 0; dt < 16; ++dt)
#pragma unroll
        for (int r = 0; r < 4; ++r) {
          int d = dt * 16 + 4 * g + r;
          *(unsigned short*)((char*)buf + swzO(d, qcol * 2)) = f2bf(acco[qt][dt][r] * inv[qt]);
        }
    }
  }
  __syncthreads();
  {
    int d = tid & 255, half = tid >> 8;
    float m = -1e30f;
    for (int i = 0; i < 8; ++i) {
      u16x8 vv = *(const u16x8*)((char*)buf + swzO(d, half * 128 + i * 16));
#pragma unroll
      for (int j = 0; j < 8; ++j) m = fmaxf(m, bf2f(vv[j]));
    }
    partial[(((size_t)b * 4 + tt) * 2 + half) * 256 + d] = m;
  }
}

// ---------- kernel 3: pooled = max_tiles + le; out = sigmoid(pooled @ w_out + b_out) ----------
__global__ __launch_bounds__(256) void finalize(
    const float* __restrict__ partial, const float* __restrict__ emb,
    const int* __restrict__ labels, const float* __restrict__ w_out,
    const float* __restrict__ b_out, float* __restrict__ out) {
  int b = blockIdx.x, t = threadIdx.x;
  float m = -1e30f;
#pragma unroll
  for (int s8 = 0; s8 < 8; ++s8)
    m = fmaxf(m, partial[((size_t)b * 8 + s8) * 256 + t]);
  m += emb[labels[b] * 256 + t];
  __shared__ float red[256];
  red[t] = m * w_out[t];
  __syncthreads();
  for (int s = 128; s > 0; s >>= 1) {
    if (t < s) red[t] += red[t + s];
    __syncthreads();
  }
  if (t == 0) out[b] = 1.f / (1.f + __expf(-(red[0] + b_out[0])));
}

extern "C" void kernel_launch(void* const* d_in, const int* in_sizes, int n_in,
                              void* d_out, int out_size, void* d_ws, size_t ws_size,
                              hipStream_t stream) {
  const float* traj   = (const float*)d_in[0];
  const int*   labels = (const int*)d_in[1];
  const float* h      = (const float*)d_in[2];
  const int*   vlen   = (const int*)d_in[3];
  const float* emb    = (const float*)d_in[4];
  const float* w_mlp  = (const float*)d_in[5];
  const float* b_mlp  = (const float*)d_in[6];
  const float* ln_g   = (const float*)d_in[7];
  const float* ln_b   = (const float*)d_in[8];
  const float* wq     = (const float*)d_in[9];
  const float* bq     = (const float*)d_in[10];
  const float* wk     = (const float*)d_in[11];
  const float* bk     = (const float*)d_in[12];
  const float* wv     = (const float*)d_in[13];
  const float* bv     = (const float*)d_in[14];
  const float* w_out  = (const float*)d_in[15];
  const float* b_out  = (const float*)d_in[16];
  float* out = (float*)d_out;

  unsigned short* kb   = (unsigned short*)d_ws;              // [64*512][256]
  unsigned short* vT   = kb + (size_t)32768 * 256;           // [B][256][512]
  unsigned short* wqPk = vT + (size_t)32768 * 256;           // K-chunked weights
  unsigned short* wkPk = wqPk + 65536;
  unsigned short* wvPk = wkPk + 65536;
  float* lnsc    = (float*)(wvPk + 65536);                   // 9 scalars (pad 16)
  float* partial = lnsc + 16;                                // [64][4][2][256]
  int*   tasktab = (int*)(partial + 64 * 8 * 256);           // [256]

  setup<<<50, 256, 0, stream>>>(wq, wk, wv, wqPk, wkPk, wvPk, w_mlp, b_mlp, lnsc,
                                vlen, tasktab);
  gemms<<<512, 512, 0, stream>>>(h, vlen, wkPk, bk, wvPk, bv, kb, vT);
  attn<<<256, 512, 0, stream>>>(traj, labels, emb, w_mlp, b_mlp, ln_g, ln_b, lnsc,
                                wqPk, bq, kb, vT, vlen, tasktab, partial);
  finalize<<<64, 256, 0, stream>>>(partial, emb, labels, w_out, b_out, out);
}

// Round 12
// 68.810 us; speedup vs baseline: 1.7536x; 1.7536x over previous
//
#include <hip/hip_runtime.h>
#include <math.h>

typedef float f32x4 __attribute__((ext_vector_type(4)));
typedef __bf16 bf16x8 __attribute__((ext_vector_type(8)));
typedef unsigned short u16x8 __attribute__((ext_vector_type(8)));
typedef unsigned short u16x4 __attribute__((ext_vector_type(4)));
typedef unsigned int u32x4 __attribute__((ext_vector_type(4)));

#define MFMA(a, b, c) __builtin_amdgcn_mfma_f32_16x16x32_bf16((a), (b), (c), 0, 0, 0)

static __device__ __forceinline__ unsigned short f2bf(float f) {
  unsigned u = __float_as_uint(f);
  u += 0x7FFFu + ((u >> 16) & 1u);  // RNE
  return (unsigned short)(u >> 16);
}
static __device__ __forceinline__ float bf2f(unsigned short s) {
  return __uint_as_float(((unsigned)s) << 16);
}
static __device__ __forceinline__ unsigned cvt_pk(float lo, float hi) {  // RNE, 1 instr
  unsigned r;
  asm("v_cvt_pk_bf16_f32 %0, %1, %2" : "=v"(r) : "v"(lo), "v"(hi));
  return r;
}

// Bijective XOR swizzles (byte addresses); all in-loop patterns <=2-way (free).
static __device__ __forceinline__ int swz512(int row, int col) {  // rowbytes 512
  return row * 512 + (col ^ ((((row & 7) ^ (col >> 6)) & 7) << 4));
}
static __device__ __forceinline__ int swzV(int d, int col) {      // rowbytes 64
  return d * 64 + (col ^ (((d >> 1) & 3) << 4));
}
static __device__ __forceinline__ int swzO64(int d, int col) {    // rowbytes 128
  return d * 128 + (col ^ ((d & 7) << 4));
}

// ---------- kernel 0 (setup): weight repack (K-chunked) + LN scalars + task sort ----------
// wPk layout: [kk(8)][d(256)][e'(32)]  where element (d,e) -> chunk e>>5, minor e&31.
__global__ __launch_bounds__(256) void setup(
    const float* __restrict__ w0m, const float* __restrict__ w1m, const float* __restrict__ w2m,
    unsigned short* __restrict__ t0m, unsigned short* __restrict__ t1m, unsigned short* __restrict__ t2m,
    const float* __restrict__ w_mlp, const float* __restrict__ b_mlp, float* __restrict__ lnsc,
    const int* __restrict__ vlen, int* __restrict__ tasktab) {
  int bid = blockIdx.x;
  int t = threadIdx.x;
  if (bid == 48) {  // 9 LN scalars: sums of {w0,w1,b, w0^2,w1^2,w0w1,w0b,w1b,b^2}
    float w0 = w_mlp[t], w1 = w_mlp[256 + t], bb = b_mlp[t];
    float v[9] = {w0, w1, bb, w0 * w0, w1 * w1, w0 * w1, w0 * bb, w1 * bb, bb * bb};
    __shared__ float red[4][9];
#pragma unroll
    for (int j = 0; j < 9; ++j) {
      float s = v[j];
#pragma unroll
      for (int off = 32; off >= 1; off >>= 1) s += __shfl_xor(s, off, 64);
      v[j] = s;
    }
    if ((t & 63) == 0)
      for (int j = 0; j < 9; ++j) red[t >> 6][j] = v[j];
    __syncthreads();
    if (t < 9) lnsc[t] = red[0][t] + red[1][t] + red[2][t] + red[3][t];
    return;
  }
  if (bid == 49) {  // sort batches by vl desc; paired task table (512 tasks of 64 queries)
    __shared__ int srank[64];
    if (t < 64) {
      int vb = vlen[t], r = 0;
      for (int j = 0; j < 64; ++j) {
        int vj = vlen[j];
        r += (vj > vb) || (vj == vb && j < t);
      }
      srank[r] = t;
    }
    __syncthreads();
    if (t < 64) {
      int r = t;                 // rank (0 = longest)
      int b1 = srank[r];         // long batch -> tiles 0..3 in first half
      int b2 = srank[63 - r];    // short batch -> tiles 4..7 in second half (same CU slot)
      int xcd = r & 7, a = r >> 3;
      for (int tt = 0; tt < 4; ++tt) {
        tasktab[(a * 4 + tt) * 8 + xcd] = (b1 << 3) | tt;
        tasktab[256 + (a * 4 + tt) * 8 + xcd] = (b2 << 3) | (tt + 4);
      }
    }
    return;
  }
  // transpose + K-chunk pack: element (e,d) of w -> wPk[e>>5][d][e&31]
  int m = bid >> 4, t16 = bid & 15;
  const float* w = (m == 0) ? w0m : (m == 1) ? w1m : w2m;
  unsigned short* o = (m == 0) ? t0m : (m == 1) ? t1m : t2m;
  __shared__ float sm[64][65];
  int bi = t16 >> 2, bj = t16 & 3;
  for (int kb = 0; kb < 16; ++kb) {
    int idx = kb * 256 + t;
    int r = idx >> 6, c = idx & 63;
    sm[r][c] = w[(bi * 64 + r) * 256 + bj * 64 + c];
  }
  __syncthreads();
  for (int kb = 0; kb < 16; ++kb) {
    int idx = kb * 256 + t;
    int r = idx >> 6, c = idx & 63;
    int d = bj * 64 + r, e = bi * 64 + c;
    o[(e >> 5) * 8192 + d * 32 + (e & 31)] = f2bf(sm[c][r]);
  }
}

// ---------- barrier-free GEMM: B fragments stream straight from global (L2-hot) ----------
static __device__ __forceinline__ void gemm_direct(
    const unsigned short* __restrict__ Bpk, const unsigned short* Alds,
    int w, int g, int c15, f32x4 (&acc)[4][4]) {
  const unsigned short* bp = Bpk + (w * 64 + c15) * 32 + 8 * g;
#pragma unroll
  for (int c = 0; c < 8; ++c) {
    bf16x8 bfv[4];
#pragma unroll
    for (int nt = 0; nt < 4; ++nt)
      bfv[nt] = *(const bf16x8*)(bp + c * 8192 + nt * 512);
    bf16x8 af[4];
#pragma unroll
    for (int at = 0; at < 4; ++at)
      af[at] = *(const bf16x8*)((char*)Alds + swz512(at * 16 + c15, c * 64 + 16 * g));
    __builtin_amdgcn_s_setprio(1);
#pragma unroll
    for (int at = 0; at < 4; ++at)
#pragma unroll
      for (int nt = 0; nt < 4; ++nt) acc[at][nt] = MFMA(af[at], bfv[nt], acc[at][nt]);
    __builtin_amdgcn_s_setprio(0);
  }
}

// ---------- kernel 1: fused k+v projections, wave-split (512 blocks x 512 thr) ----------
// Waves 0-3: V GEMM + direct vT stores. Waves 4-7: K GEMM -> Klds transpose buffer.
__global__ __launch_bounds__(512, 4) void gemms(
    const float* __restrict__ h, const int* __restrict__ vlen,
    const unsigned short* __restrict__ wkPk, const float* __restrict__ bk,
    const unsigned short* __restrict__ wvPk, const float* __restrict__ bv,
    unsigned short* __restrict__ kout, unsigned short* __restrict__ vT) {
  __shared__ unsigned short Alds[64 * 256];  // 32KB
  __shared__ unsigned short Klds[64 * 256];  // 32KB
  int tid = threadIdx.x, w = tid >> 6, lane = tid & 63, g = lane >> 4, c15 = lane & 15;
  int tile = blockIdx.x;
  int b = tile >> 3;
  int nbase = (tile & 7) * 64;
  if (nbase >= vlen[b]) return;
  f32x4 acc[4][4];
  {
    const float* hb = h + (size_t)tile * 16384;
    f32x4 ha[4], hc[4];
#pragma unroll
    for (int i = 0; i < 4; ++i) {  // 2KB contiguous per wave-instruction pair
      ha[i] = *(const f32x4*)(hb + i * 4096 + tid * 8);
      hc[i] = *(const f32x4*)(hb + i * 4096 + tid * 8 + 4);
    }
#pragma unroll
    for (int i = 0; i < 4; ++i) {
      u16x8 pk;
#pragma unroll
      for (int j = 0; j < 4; ++j) { pk[j] = f2bf(ha[i][j]); pk[j + 4] = f2bf(hc[i][j]); }
      *(u16x8*)((char*)Alds + swz512(i * 16 + (tid >> 5), (tid & 31) * 16)) = pk;
    }
  }
#pragma unroll
  for (int a = 0; a < 4; ++a)
#pragma unroll
    for (int n = 0; n < 4; ++n) acc[a][n] = (f32x4){0.f, 0.f, 0.f, 0.f};
  __syncthreads();

  int w4 = w & 3;
  if (w < 4) {  // --- V: direct-to-global vT stores ---
    gemm_direct(wvPk, Alds, w4, g, c15, acc);
#pragma unroll
    for (int at = 0; at < 4; ++at)
#pragma unroll
      for (int nt = 0; nt < 4; ++nt) {
        int col = w4 * 64 + nt * 16 + c15;
        float bb = bv[col];
        u16x4 o;
#pragma unroll
        for (int r = 0; r < 4; ++r) o[r] = f2bf(acc[at][nt][r] + bb);
        *(u16x4*)(vT + (size_t)b * 131072 + (size_t)col * 512 + nbase + at * 16 + 4 * g) = o;
      }
  } else {  // --- K: into Klds for transpose ---
    gemm_direct(wkPk, Alds, w4, g, c15, acc);
#pragma unroll
    for (int at = 0; at < 4; ++at)
#pragma unroll
      for (int nt = 0; nt < 4; ++nt) {
        int col = w4 * 64 + nt * 16 + c15;
        float bb = bk[col];
#pragma unroll
        for (int r = 0; r < 4; ++r)
          *(unsigned short*)((char*)Klds + swz512(at * 16 + 4 * g + r, col * 2)) =
              f2bf(acc[at][nt][r] + bb);
      }
  }
  __syncthreads();
  if (tid < 256) {  // coalesced k store (v-waves, now free)
    int row = tid >> 2;
    for (int i = 0; i < 8; ++i) {
      int colb = (tid & 3) * 128 + i * 16;
      u16x8 vv = *(const u16x8*)((char*)Klds + swz512(row, colb));
      *(u16x8*)(kout + (size_t)(tile * 64 + row) * 256 + colb / 2) = vv;
    }
  }
}

// ---------- kernel 2: attention + fused q projection ----------
// 512 blocks x 256 thr / 4 waves, ALL consumers (16 queries each) — R9 loop at
// half size. LDS 64KB -> 2 independent blocks/CU (cross-block TLP + long/short
// task pairing fixes the 1-block/CU makespan imbalance).
__global__ __launch_bounds__(256, 2) void attn(
    const float* __restrict__ traj, const int* __restrict__ labels,
    const float* __restrict__ emb, const float* __restrict__ w_mlp,
    const float* __restrict__ b_mlp, const float* __restrict__ ln_g,
    const float* __restrict__ ln_b, const float* __restrict__ lnsc,
    const unsigned short* __restrict__ wqPk, const float* __restrict__ bq,
    const unsigned short* __restrict__ k, const unsigned short* __restrict__ vT,
    const int* __restrict__ valid_len, const int* __restrict__ tasktab,
    float* __restrict__ partial) {
  __shared__ unsigned short buf[2][16384];  // 64KB: x/q tile overlay, then K|V double-buffer

  int task = tasktab[blockIdx.x];
  int b = task >> 3, tt = task & 7;       // tt: 64-query tile (0..7)
  int tid = threadIdx.x, w = tid >> 6, lane = tid & 63, g = lane >> 4, c15 = lane & 15;
  int vl = valid_len[b];
  int nit = (vl + 31) >> 5;

  // ---- stage x tile [64 rows][256] (LN(traj@w_mlp+b)+le) into buf (256 thr) ----
  {
    int rrow = tid >> 5, cb = (tid & 31) * 8;
    int lab = labels[b];
    f32x4 wa0 = *(const f32x4*)(w_mlp + cb), wa1 = *(const f32x4*)(w_mlp + cb + 4);
    f32x4 wb0 = *(const f32x4*)(w_mlp + 256 + cb), wb1 = *(const f32x4*)(w_mlp + 256 + cb + 4);
    f32x4 bm0 = *(const f32x4*)(b_mlp + cb), bm1 = *(const f32x4*)(b_mlp + cb + 4);
    f32x4 g0 = *(const f32x4*)(ln_g + cb), g1 = *(const f32x4*)(ln_g + cb + 4);
    f32x4 lb0 = *(const f32x4*)(ln_b + cb), lb1 = *(const f32x4*)(ln_b + cb + 4);
    f32x4 le0 = *(const f32x4*)(emb + lab * 256 + cb), le1 = *(const f32x4*)(emb + lab * 256 + cb + 4);
    float s0 = lnsc[0], s1 = lnsc[1], s2 = lnsc[2], s3 = lnsc[3], s4_ = lnsc[4],
          s5 = lnsc[5], s6 = lnsc[6], s7 = lnsc[7], s8 = lnsc[8];
#pragma unroll
    for (int i = 0; i < 8; ++i) {
      int row = i * 8 + rrow, grow = b * 512 + tt * 64 + row;
      float t0 = traj[grow * 2], t1 = traj[grow * 2 + 1];
      float mu = (t0 * s0 + t1 * s1 + s2) * (1.f / 256.f);
      float ea2 = (t0 * t0 * s3 + t1 * t1 * s4_ + s8 +
                   2.f * (t0 * t1 * s5 + t0 * s6 + t1 * s7)) * (1.f / 256.f);
      float rstd = rsqrtf(ea2 - mu * mu + 1e-5f);
      u16x8 pk;
#pragma unroll
      for (int j = 0; j < 4; ++j) {
        float a0 = t0 * wa0[j] + t1 * wb0[j] + bm0[j];
        float y0 = (a0 - mu) * rstd * g0[j] + lb0[j];
        pk[j] = f2bf((y0 > 0.f ? y0 : 0.01f * y0) + le0[j]);
        float a1 = t0 * wa1[j] + t1 * wb1[j] + bm1[j];
        float y1 = (a1 - mu) * rstd * g1[j] + lb1[j];
        pk[j + 4] = f2bf((y1 > 0.f ? y1 : 0.01f * y1) + le1[j]);
      }
      *(u16x8*)((char*)buf + swz512(row, cb * 2)) = pk;
    }
  }
  __syncthreads();

  // ---- q GEMM 64x256 over 4 waves (wave w -> cols w*64..); write q -> buf+32KB ----
  {
    f32x4 qacc[4][4];
#pragma unroll
    for (int a = 0; a < 4; ++a)
#pragma unroll
      for (int n = 0; n < 4; ++n) qacc[a][n] = (f32x4){0.f, 0.f, 0.f, 0.f};
    gemm_direct(wqPk, (const unsigned short*)buf, w, g, c15, qacc);
    __syncthreads();  // done reading x
#pragma unroll
    for (int nt = 0; nt < 4; ++nt) {
      int col = w * 64 + nt * 16 + c15;
      float bb = bq[col];
#pragma unroll
      for (int at = 0; at < 4; ++at)
#pragma unroll
        for (int r = 0; r < 4; ++r)
          *(unsigned short*)((char*)buf + 32768 + swz512(at * 16 + 4 * g + r, col * 2)) =
              f2bf(qacc[at][nt][r] + bb);
    }
  }
  __syncthreads();
  bf16x8 qf[8];  // this wave's 16 queries: w*16 + c15
#pragma unroll
  for (int kk = 0; kk < 8; ++kk)
    qf[kk] = *(const bf16x8*)((char*)buf + 32768 + swz512(w * 16 + c15, kk * 64 + 16 * g));
  __syncthreads();  // q-tile consumed; buf free for K/V

  f32x4 acco[16];
#pragma unroll
  for (int i = 0; i < 16; ++i) acco[i] = (f32x4){0.f, 0.f, 0.f, 0.f};
  float rs = 0.f;

  const unsigned short* kbase = k + (size_t)b * 512 * 256;
  const unsigned short* vbase = vT + (size_t)b * 131072;
  u16x8 kpre[4], vpre[4];

  // chunk 0 -> regs -> buf0
#pragma unroll
  for (int i = 0; i < 4; ++i) {
    int idx = tid + 256 * i, key = idx >> 5, s = idx & 31;
    kpre[i] = *(const u16x8*)(kbase + (size_t)key * 256 + s * 8);
  }
#pragma unroll
  for (int i = 0; i < 4; ++i) {
    int idx = tid + 256 * i, d = idx >> 2, s = idx & 3;
    vpre[i] = *(const u16x8*)(vbase + (size_t)d * 512 + s * 8);
  }
#pragma unroll
  for (int i = 0; i < 4; ++i) {
    int idx = tid + 256 * i, key = idx >> 5, s = idx & 31;
    *(u16x8*)((char*)buf[0] + swz512(key, s * 16)) = kpre[i];
  }
#pragma unroll
  for (int i = 0; i < 4; ++i) {
    int idx = tid + 256 * i, d = idx >> 2, s = idx & 3;
    *(u16x8*)((char*)(buf[0] + 8192) + swzV(d, s * 16)) = vpre[i];
  }

  for (int it = 0; it < nit; ++it) {
    int cur = it & 1;
    __syncthreads();  // buf[cur] published; buf[cur^1] free
    bool pf = (it + 1 < nit);
    if (pf) {
      int n1 = (it + 1) * 32;
#pragma unroll
      for (int i = 0; i < 4; ++i) {
        int idx = tid + 256 * i, key = idx >> 5, s = idx & 31;
        kpre[i] = *(const u16x8*)(kbase + (size_t)(n1 + key) * 256 + s * 8);
      }
#pragma unroll
      for (int i = 0; i < 4; ++i) {
        int idx = tid + 256 * i, d = idx >> 2, s = idx & 3;
        vpre[i] = *(const u16x8*)(vbase + (size_t)d * 512 + n1 + s * 8);
      }
    }
    unsigned short* Klds = buf[cur];
    unsigned short* Vlds = buf[cur] + 8192;
    int n0 = it * 32;

    // QK^T swapped: lane holds q=c15, keys 4g+r per 16-chunk
    float p[2][4];
    unsigned u01[2], u23[2];
#pragma unroll
    for (int c = 0; c < 2; ++c) {
      f32x4 s4 = (f32x4){0.f, 0.f, 0.f, 0.f};
      __builtin_amdgcn_s_setprio(1);
#pragma unroll
      for (int kk = 0; kk < 8; ++kk) {
        bf16x8 kf = *(const bf16x8*)((char*)Klds + swz512(c * 16 + c15, kk * 64 + 16 * g));
        s4 = MFMA(kf, qf[kk], s4);
      }
      __builtin_amdgcn_s_setprio(0);
#pragma unroll
      for (int r = 0; r < 4; ++r) {
        int key = n0 + c * 16 + 4 * g + r;
        float pv = (key < vl) ? __expf(s4[r] * 0.0625f) : 0.f;
        p[c][r] = pv;
        rs += pv;
      }
      u01[c] = cvt_pk(p[c][0], p[c][1]);
      u23[c] = cvt_pk(p[c][2], p[c][3]);
    }
    // g-exchange: lane needs P[q=c15][keys 8g..8g+7]
    int srcA = c15 | ((lane & 16) << 1);
    int srcB = srcA + 16;
    unsigned x0a = (unsigned)__shfl((int)u01[0], srcA, 64);
    unsigned x1a = (unsigned)__shfl((int)u01[1], srcA, 64);
    unsigned x0b = (unsigned)__shfl((int)u23[0], srcA, 64);
    unsigned x1b = (unsigned)__shfl((int)u23[1], srcA, 64);
    unsigned x0c = (unsigned)__shfl((int)u01[0], srcB, 64);
    unsigned x1c = (unsigned)__shfl((int)u01[1], srcB, 64);
    unsigned x0d = (unsigned)__shfl((int)u23[0], srcB, 64);
    unsigned x1d = (unsigned)__shfl((int)u23[1], srcB, 64);
    bool hi = g >= 2;
    union { u32x4 u; bf16x8 v; } pa;
    pa.u[0] = hi ? x1a : x0a;
    pa.u[1] = hi ? x1b : x0b;
    pa.u[2] = hi ? x1c : x0c;
    pa.u[3] = hi ? x1d : x0d;
    // PV swapped: O^T[d][q] += V^T * P^T
    __builtin_amdgcn_s_setprio(1);
#pragma unroll
    for (int dt = 0; dt < 16; ++dt) {
      bf16x8 vf = *(const bf16x8*)((char*)Vlds + swzV(dt * 16 + c15, 16 * g));
      acco[dt] = MFMA(vf, pa.v, acco[dt]);
    }
    __builtin_amdgcn_s_setprio(0);
    // store next chunk into the other buffer (no barrier needed: it was free)
    if (pf) {
      unsigned short* Kn = buf[cur ^ 1];
      unsigned short* Vn = buf[cur ^ 1] + 8192;
#pragma unroll
      for (int i = 0; i < 4; ++i) {
        int idx = tid + 256 * i, key = idx >> 5, s = idx & 31;
        *(u16x8*)((char*)Kn + swz512(key, s * 16)) = kpre[i];
      }
#pragma unroll
      for (int i = 0; i < 4; ++i) {
        int idx = tid + 256 * i, d = idx >> 2, s = idx & 3;
        *(u16x8*)((char*)Vn + swzV(d, s * 16)) = vpre[i];
      }
    }
  }
  rs += __shfl_xor(rs, 16, 64);
  rs += __shfl_xor(rs, 32, 64);
  float inv = 1.f / rs;  // per-lane: q = c15 of wave w
  __syncthreads();       // all compute done; overlay buf as O^T[256 d][64 q] bf16 (32KB)
  int qcol = w * 16 + c15;  // 0..63
#pragma unroll
  for (int dt = 0; dt < 16; ++dt)
#pragma unroll
    for (int r = 0; r < 4; ++r) {
      int d = dt * 16 + 4 * g + r;
      *(unsigned short*)((char*)buf + swzO64(d, qcol * 2)) = f2bf(acco[dt][r] * inv);
    }
  __syncthreads();
  {
    int d = tid;  // 0..255
    float m = -1e30f;
    for (int i = 0; i < 8; ++i) {
      u16x8 vv = *(const u16x8*)((char*)buf + swzO64(d, i * 16));
#pragma unroll
      for (int j = 0; j < 8; ++j) m = fmaxf(m, bf2f(vv[j]));
    }
    partial[((size_t)b * 8 + tt) * 256 + d] = m;
  }
}

// ---------- kernel 3: pooled = max_tiles + le; out = sigmoid(pooled @ w_out + b_out) ----------
__global__ __launch_bounds__(256) void finalize(
    const float* __restrict__ partial, const float* __restrict__ emb,
    const int* __restrict__ labels, const float* __restrict__ w_out,
    const float* __restrict__ b_out, float* __restrict__ out) {
  int b = blockIdx.x, t = threadIdx.x;
  float m = -1e30f;
#pragma unroll
  for (int s8 = 0; s8 < 8; ++s8)
    m = fmaxf(m, partial[((size_t)b * 8 + s8) * 256 + t]);
  m += emb[labels[b] * 256 + t];
  __shared__ float red[256];
  red[t] = m * w_out[t];
  __syncthreads();
  for (int s = 128; s > 0; s >>= 1) {
    if (t < s) red[t] += red[t + s];
    __syncthreads();
  }
  if (t == 0) out[b] = 1.f / (1.f + __expf(-(red[0] + b_out[0])));
}

extern "C" void kernel_launch(void* const* d_in, const int* in_sizes, int n_in,
                              void* d_out, int out_size, void* d_ws, size_t ws_size,
                              hipStream_t stream) {
  const float* traj   = (const float*)d_in[0];
  const int*   labels = (const int*)d_in[1];
  const float* h      = (const float*)d_in[2];
  const int*   vlen   = (const int*)d_in[3];
  const float* emb    = (const float*)d_in[4];
  const float* w_mlp  = (const float*)d_in[5];
  const float* b_mlp  = (const float*)d_in[6];
  const float* ln_g   = (const float*)d_in[7];
  const float* ln_b   = (const float*)d_in[8];
  const float* wq     = (const float*)d_in[9];
  const float* bq     = (const float*)d_in[10];
  const float* wk     = (const float*)d_in[11];
  const float* bk     = (const float*)d_in[12];
  const float* wv     = (const float*)d_in[13];
  const float* bv     = (const float*)d_in[14];
  const float* w_out  = (const float*)d_in[15];
  const float* b_out  = (const float*)d_in[16];
  float* out = (float*)d_out;

  unsigned short* kb   = (unsigned short*)d_ws;              // [64*512][256]
  unsigned short* vT   = kb + (size_t)32768 * 256;           // [B][256][512]
  unsigned short* wqPk = vT + (size_t)32768 * 256;           // K-chunked weights
  unsigned short* wkPk = wqPk + 65536;
  unsigned short* wvPk = wkPk + 65536;
  float* lnsc    = (float*)(wvPk + 65536);                   // 9 scalars (pad 16)
  float* partial = lnsc + 16;                                // [64][8][256]
  int*   tasktab = (int*)(partial + 64 * 8 * 256);           // [512]

  setup<<<50, 256, 0, stream>>>(wq, wk, wv, wqPk, wkPk, wvPk, w_mlp, b_mlp, lnsc,
                                vlen, tasktab);
  gemms<<<512, 512, 0, stream>>>(h, vlen, wkPk, bk, wvPk, bv, kb, vT);
  attn<<<512, 256, 0, stream>>>(traj, labels, emb, w_mlp, b_mlp, ln_g, ln_b, lnsc,
                                wqPk, bq, kb, vT, vlen, tasktab, partial);
  finalize<<<64, 256, 0, stream>>>(partial, emb, labels, w_out, b_out, out);
}